// Round 2
// baseline (337.072 us; speedup 1.0000x reference)
//
#include <hip/hip_runtime.h>
#include <math.h>

// GATv2 2-layer: N=50000, E=800000, HEADS=8, C=32, ODIM=256, IN_C=64
#define HEADS 8
#define CDIM 32
#define ODIM 256

typedef _Float16 h2 __attribute__((ext_vector_type(2)));
typedef _Float16 h4 __attribute__((ext_vector_type(4)));
typedef _Float16 h8 __attribute__((ext_vector_type(8)));
typedef float f32x4 __attribute__((ext_vector_type(4)));
union H4 { h4 v; h2 p[2]; };

#if __has_builtin(__builtin_amdgcn_fdot2)
#define FDOT2(a,b,c) __builtin_amdgcn_fdot2((a),(b),(c),false)
#else
static __device__ __forceinline__ float fdot2_sw(h2 a, h2 b, float c){
  return fmaf((float)a.x, (float)b.x, fmaf((float)a.y, (float)b.y, c));
}
#define FDOT2(a,b,c) fdot2_sw((a),(b),(c))
#endif

__device__ __forceinline__ float lrelu(float v, float s){ return fmaxf(v, s*v); }

// ---- 3-phase parallel scan ----
__global__ void block_sum_kernel(const int* __restrict__ counts, int* __restrict__ bsums, int n){
  int i = blockIdx.x*256 + threadIdx.x;
  int v = (i < n) ? counts[i] : 0;
#pragma unroll
  for (int off=1; off<64; off<<=1) v += __shfl_xor(v, off);
  __shared__ int ws[4];
  int lane = threadIdx.x & 63, w = threadIdx.x >> 6;
  if (lane == 0) ws[w] = v;
  __syncthreads();
  if (threadIdx.x == 0) bsums[blockIdx.x] = ws[0]+ws[1]+ws[2]+ws[3];
}

__global__ __launch_bounds__(1024) void scan_bsums_kernel(int* __restrict__ bsums, int nb){
  __shared__ int s[1024];
  int t = threadIdx.x;
  int v = (t < nb) ? bsums[t] : 0;
  s[t] = v;
  __syncthreads();
  for (int off=1; off<1024; off<<=1){
    int u = (t >= off) ? s[t-off] : 0;
    __syncthreads();
    s[t] += u;
    __syncthreads();
  }
  if (t < nb) bsums[t] = s[t] - v;   // exclusive
}

__global__ void local_scan_kernel(const int* __restrict__ counts, const int* __restrict__ bsums,
                                  int* __restrict__ indptr, int n){
  __shared__ int s[256];
  int t = threadIdx.x;
  int i = blockIdx.x*256 + t;
  int v = (i < n) ? counts[i] : 0;
  s[t] = v;
  __syncthreads();
  for (int off=1; off<256; off<<=1){
    int u = (t >= off) ? s[t-off] : 0;
    __syncthreads();
    s[t] += u;
    __syncthreads();
  }
  int excl = s[t] - v + bsums[blockIdx.x];
  if (i < n) indptr[i] = excl;
  if (i == n-1) indptr[n] = excl + v;
}

// atomic-free scatter: csr[indptr[d] + rank] = s. Ranks per dst are a
// permutation of 0..cnt-1 -> csr[beg,end) fully written (poison-proof).
__global__ void scatter_kernel(const int* __restrict__ src, const int* __restrict__ dst,
                               const int* __restrict__ rank, const int* __restrict__ indptr,
                               int* __restrict__ csr_src, int e){
  int i = blockIdx.x*256 + threadIdx.x;
  if (i < e){
    int r = rank[i];
    if (r >= 0){
      int d = dst[i];
      csr_src[indptr[d] + r] = src[i];
    }
  }
}

// ---------------- MFMA GEMM: out[n,512] = X[n,K] * [Wl;Wr]^T + [bl;br] ----------------
// v_mfma_f32_16x16x32_f16. A operand = W (rows=channels), B operand = X
// (cols=nodes): C/D layout col=lane&15 (node), row=(lane>>4)*4+reg (channel)
// -> each frag epilogues as ONE contiguous h4 (8B) store per lane.
// X tile (64 nodes x K) staged LDS fp16, +8-half row pad (stride 144B/80B ->
// 2-way bank alias = free). W frags loaded direct from global (L2-resident,
// 64-128KB total) with inline f32->f16 cvt: no W staging, one barrier total.
// Block = 4 waves x 64ch = 64 nodes x 256 ch; grid (ntiles64, 2 [+1 count]).
// FUSE_COUNT: y==0 slice runs CSR count+rank over ALL x-blocks (the MFMA gemm
// no longer hides it, so give it the full grid's parallelism).
template<int K, bool FUSE_COUNT>
__global__ __launch_bounds__(256, 2) void gemm_mfma(const float* __restrict__ X,
    const float* __restrict__ Wl, const float* __restrict__ bl,
    const float* __restrict__ Wr, const float* __restrict__ br,
    _Float16* __restrict__ outl, _Float16* __restrict__ outr, int n,
    const int* __restrict__ src, const int* __restrict__ dst,
    int* __restrict__ counts, int* __restrict__ rank, int e){
  if (FUSE_COUNT && blockIdx.y == 0){
    int stride = gridDim.x*256;
    for (int i = blockIdx.x*256 + threadIdx.x; i < e; i += stride){
      int s = src[i], d = dst[i];
      int r = -1;
      if (s != d) r = atomicAdd(counts + d, 1);   // src==dst masked (PyG removes)
      rank[i] = r;
    }
    return;
  }
  const int KP = K + 8;
  __shared__ __align__(16) _Float16 Xs[64*(K+8)];
  int t = threadIdx.x;
  int n0 = blockIdx.x*64;
  int ybase = FUSE_COUNT ? (blockIdx.y-1) : blockIdx.y;

  // stage X tile, fp32 -> fp16
  for (int idx = t; idx < 64*(K/4); idx += 256){
    int row = idx/(K/4), c = (idx%(K/4))*4;
    int node = n0 + row; if (node >= n) node = n-1;   // clamp; stores guarded
    float4 xv = *(const float4*)(X + (size_t)node*K + c);
    h4 hv = {(_Float16)xv.x, (_Float16)xv.y, (_Float16)xv.z, (_Float16)xv.w};
    *(h4*)(Xs + row*KP + c) = hv;
  }
  __syncthreads();

  int wave = t >> 6, lane = t & 63;
  int co = ybase*256 + wave*64;           // global channel base (0..511)
  const float* W   = (co < 256) ? Wl : Wr;
  const float* Bv  = (co < 256) ? bl : br;
  _Float16* outp   = (co < 256) ? outl : outr;
  int lco = co & 255;
  int lr = lane & 15, lg = lane >> 4;

  f32x4 acc[4][4];
#pragma unroll
  for (int c = 0; c < 4; ++c)
#pragma unroll
    for (int m = 0; m < 4; ++m) acc[c][m] = (f32x4){0.f, 0.f, 0.f, 0.f};

#pragma unroll
  for (int ks = 0; ks < K/32; ++ks){
    int k0 = ks*32 + lg*8;
    h8 a[4], b[4];
#pragma unroll
    for (int c = 0; c < 4; ++c){                 // A: W[ch][k0..k0+7], cvt f16
      const float* wp = W + (size_t)(lco + c*16 + lr)*K + k0;
      float4 w0 = *(const float4*)(wp);
      float4 w1 = *(const float4*)(wp + 4);
      a[c] = (h8){(_Float16)w0.x,(_Float16)w0.y,(_Float16)w0.z,(_Float16)w0.w,
                  (_Float16)w1.x,(_Float16)w1.y,(_Float16)w1.z,(_Float16)w1.w};
    }
#pragma unroll
    for (int m = 0; m < 4; ++m)                  // B: Xs[node][k0..k0+7]
      b[m] = *(const h8*)(Xs + (m*16 + lr)*KP + k0);
#pragma unroll
    for (int c = 0; c < 4; ++c)
#pragma unroll
      for (int m = 0; m < 4; ++m)
        acc[c][m] = __builtin_amdgcn_mfma_f32_16x16x32_f16(a[c], b[m], acc[c][m], 0, 0, 0);
  }

  // epilogue: frag (c,m): lane -> node n0+m*16+(lane&15), channels lco+c*16+lg*4+[0..3]
#pragma unroll
  for (int c = 0; c < 4; ++c){
    int ch = lco + c*16 + lg*4;
    float4 bb = *(const float4*)(Bv + ch);
#pragma unroll
    for (int m = 0; m < 4; ++m){
      int node = n0 + m*16 + lr;
      if (node < n){
        h4 o = {(_Float16)(acc[c][m][0] + bb.x), (_Float16)(acc[c][m][1] + bb.y),
                (_Float16)(acc[c][m][2] + bb.z), (_Float16)(acc[c][m][3] + bb.w)};
        *(h4*)(outp + (size_t)node*ODIM + ch) = o;
      }
    }
  }
}

// ---------------- fused edge softmax + aggregate, one wave per node ----------------
// R6-proven memory structure (1 edge/iter, depth-2 guarded prefetch, h4/lane
// coalesced 512B/wave) + packed-fp16 score path (R10/R11-proven).
__global__ __launch_bounds__(256) void edge_kernel(
    const _Float16* __restrict__ xl, const _Float16* __restrict__ xr,
    const float* __restrict__ att, const float* __restrict__ bias,
    const int* __restrict__ indptr, const int* __restrict__ csr_src,
    float* __restrict__ out, int n, int act)
{
  int wid = blockIdx.x*4 + (threadIdx.x >> 6);
  if (wid >= n) return;
  int lane = threadIdx.x & 63;
  const float LOG2E = 1.44269504088896341f;

  float4 attf = *(const float4*)(att + 4*lane);
  h2 at0 = (h2){(_Float16)(attf.x*LOG2E), (_Float16)(attf.y*LOG2E)};
  h2 at1 = (h2){(_Float16)(attf.z*LOG2E), (_Float16)(attf.w*LOG2E)};
  const h2 c02 = {(_Float16)0.2f, (_Float16)0.2f};

  H4 xrh; xrh.v = *(const h4*)(xr + (size_t)wid*ODIM + 4*lane);
  H4 self; self.v = *(const h4*)(xl + (size_t)wid*ODIM + 4*lane);

  auto score = [&](const H4& c)->float{
    h2 t0 = c.p[0] + xrh.p[0];
    h2 t1 = c.p[1] + xrh.p[1];
    h2 q0 = __builtin_elementwise_max(t0, t0 * c02);
    h2 q1 = __builtin_elementwise_max(t1, t1 * c02);
    float d = FDOT2(q0, at0, FDOT2(q1, at1, 0.f));
    d += __shfl_xor(d, 1);   // reduce over the 8 lanes of this head
    d += __shfl_xor(d, 2);
    d += __shfl_xor(d, 4);
    return d;
  };

  // self-loop seeds the accumulator
  float w0 = exp2f(score(self));
  float denom = w0;
  float4 acc;
  acc.x = w0 * (float)self.v.x;
  acc.y = w0 * (float)self.v.y;
  acc.z = w0 * (float)self.v.z;
  acc.w = w0 * (float)self.v.w;

  int beg = __builtin_amdgcn_readfirstlane(indptr[wid]);
  int end = __builtin_amdgcn_readfirstlane(indptr[wid+1]);
  int cnt = end - beg;
  H4 r0, r1;
  r0.v = (h4){}; r1.v = (h4){};
  if (cnt > 0){
    int s0 = __builtin_amdgcn_readfirstlane(csr_src[beg]);
    r0.v = *(const h4*)(xl + (size_t)s0*ODIM + 4*lane);
  }
  if (cnt > 1){
    int s1 = __builtin_amdgcn_readfirstlane(csr_src[beg+1]);
    r1.v = *(const h4*)(xl + (size_t)s1*ODIM + 4*lane);
  }
  for (int k = 0; k < cnt; ++k){
    H4 cur = r0; r0 = r1;
    if (k+2 < cnt){
      int s2 = __builtin_amdgcn_readfirstlane(csr_src[beg+k+2]);
      r1.v = *(const h4*)(xl + (size_t)s2*ODIM + 4*lane);   // prefetch 2 ahead
    }
    float pe = exp2f(score(cur));
    denom += pe;
    acc.x = fmaf(pe, (float)cur.v.x, acc.x);   // v_fma_mix (single-use cvt)
    acc.y = fmaf(pe, (float)cur.v.y, acc.y);
    acc.z = fmaf(pe, (float)cur.v.z, acc.z);
    acc.w = fmaf(pe, (float)cur.v.w, acc.w);
  }
  float inv = 1.f/denom;
  float vx = acc.x*inv, vy = acc.y*inv, vz = acc.z*inv, vw = acc.w*inv;
  // mean over heads: sum lanes {l, l^8, l^16, l^32}
  vx += __shfl_xor(vx, 8);  vx += __shfl_xor(vx, 16);  vx += __shfl_xor(vx, 32);
  vy += __shfl_xor(vy, 8);  vy += __shfl_xor(vy, 16);  vy += __shfl_xor(vy, 32);
  vz += __shfl_xor(vz, 8);  vz += __shfl_xor(vz, 16);  vz += __shfl_xor(vz, 32);
  vw += __shfl_xor(vw, 8);  vw += __shfl_xor(vw, 16);  vw += __shfl_xor(vw, 32);
  if (lane < 8){
    float4 bv = *(const float4*)(bias + 4*lane);
    float ox = vx*0.125f + bv.x;
    float oy = vy*0.125f + bv.y;
    float oz = vz*0.125f + bv.z;
    float ow = vw*0.125f + bv.w;
    if (act){
      ox = lrelu(ox, 0.01f); oy = lrelu(oy, 0.01f);
      oz = lrelu(oz, 0.01f); ow = lrelu(ow, 0.01f);
    }
    *(float4*)(out + (size_t)wid*CDIM + 4*lane) = make_float4(ox, oy, oz, ow);
  }
}

extern "C" void kernel_launch(void* const* d_in, const int* in_sizes, int n_in,
                              void* d_out, int out_size, void* d_ws, size_t ws_size,
                              hipStream_t stream){
  (void)n_in; (void)out_size; (void)ws_size;
  const float* x    = (const float*)d_in[0];
  const int*   ei   = (const int*)d_in[1];
  const float* W1l  = (const float*)d_in[2];
  const float* b1l  = (const float*)d_in[3];
  const float* W1r  = (const float*)d_in[4];
  const float* b1r  = (const float*)d_in[5];
  const float* att1 = (const float*)d_in[6];
  const float* bias1= (const float*)d_in[7];
  const float* W2l  = (const float*)d_in[8];
  const float* b2l  = (const float*)d_in[9];
  const float* W2r  = (const float*)d_in[10];
  const float* b2r  = (const float*)d_in[11];
  const float* att2 = (const float*)d_in[12];
  const float* bias2= (const float*)d_in[13];
  int n = in_sizes[0] / 64;   // 50000
  int e = in_sizes[1] / 2;    // 800000
  const int* src = ei;
  const int* dst = ei + e;

  char* ws = (char*)d_ws;
  size_t off = 0;
  auto alloc = [&](size_t bytes)->char*{
    char* p = ws + off; off += (bytes + 255) & ~(size_t)255; return p;
  };
  _Float16* xl  = (_Float16*)alloc((size_t)n*ODIM*2);  // 25.6 MB fp16
  _Float16* xr  = (_Float16*)alloc((size_t)n*ODIM*2);  // 25.6 MB fp16
  float* h      = (float*)alloc((size_t)n*CDIM*4);     // 6.4 MB layer-1 output
  int*   counts = (int*)alloc((size_t)n*4);
  int*   indptr = (int*)alloc((size_t)(n+1)*4);
  int*   rank   = (int*)alloc((size_t)e*4);
  int*   csr    = (int*)alloc((size_t)e*4);
  int*   bsums  = (int*)alloc((size_t)1024*4);

  int nblk = (n + 255) / 256;     // 196
  int nt64 = (n + 63) / 64;       // 782
  hipMemsetAsync(counts, 0, (size_t)n*4, stream);

  // layer-1 MFMA GEMM with fused CSR count (entire y==0 slice counts; the
  // MFMA gemm is too fast to hide it behind 96 blocks)
  gemm_mfma<64,true><<<dim3(nt64,3), 256, 0, stream>>>(
      x, W1l, b1l, W1r, b1r, xl, xr, n, src, dst, counts, rank, e);
  block_sum_kernel<<<nblk, 256, 0, stream>>>(counts, bsums, n);
  scan_bsums_kernel<<<1, 1024, 0, stream>>>(bsums, nblk);
  local_scan_kernel<<<nblk, 256, 0, stream>>>(counts, bsums, indptr, n);
  scatter_kernel<<<(e+255)/256, 256, 0, stream>>>(src, dst, rank, indptr, csr, e);

  edge_kernel<<<(n+3)/4, 256, 0, stream>>>(xl, xr, att1, bias1, indptr, csr, h, n, 1);
  // layer 2
  gemm_mfma<32,false><<<dim3(nt64,2), 256, 0, stream>>>(
      h, W2l, b2l, W2r, b2r, xl, xr, n, nullptr, nullptr, nullptr, nullptr, 0);
  edge_kernel<<<(n+3)/4, 256, 0, stream>>>(xl, xr, att2, bias2, indptr, csr, (float*)d_out, n, 0);
}

// Round 3
// 319.955 us; speedup vs baseline: 1.0535x; 1.0535x over previous
//
#include <hip/hip_runtime.h>
#include <math.h>

// GATv2 2-layer: N=50000, E=800000, HEADS=8, C=32, ODIM=256, IN_C=64
#define HEADS 8
#define CDIM 32
#define ODIM 256
#define BKT_SHIFT 7              // 128 nodes per bucket
#define CHUNK 2048               // edges per histogram chunk

typedef _Float16 h2 __attribute__((ext_vector_type(2)));
typedef _Float16 h4 __attribute__((ext_vector_type(4)));
typedef _Float16 h8 __attribute__((ext_vector_type(8)));
typedef float f32x4 __attribute__((ext_vector_type(4)));
union H4 { h4 v; h2 p[2]; };

#if __has_builtin(__builtin_amdgcn_fdot2)
#define FDOT2(a,b,c) __builtin_amdgcn_fdot2((a),(b),(c),false)
#else
static __device__ __forceinline__ float fdot2_sw(h2 a, h2 b, float c){
  return fmaf((float)a.x, (float)b.x, fmaf((float)a.y, (float)b.y, c));
}
#define FDOT2(a,b,c) fdot2_sw((a),(b),(c))
#endif

__device__ __forceinline__ float lrelu(float v, float s){ return fmaxf(v, s*v); }

// ================= atomic-free CSR build (bucket counting sort) =================
// R2 post-mortem: 800K device-scope atomicAdd-with-return = ~72us (each atomic
// is an independent 64B RMW at the coherence point; WRITE_SIZE showed +55MB).
// Replace with LDS-only hierarchical sort: per-chunk LDS bucket histogram ->
// per-bucket scan over chunks -> deterministic bucket-major scatter ->
// per-bucket LDS counting sort emitting csr (sequential writes) + indptr.

// pass 1: per-chunk bucket histogram + per-edge local rank (LDS atomics only)
__global__ __launch_bounds__(256) void csr_hist_kernel(
    const int* __restrict__ src, const int* __restrict__ dst,
    int* __restrict__ rank, int* __restrict__ hist, int e, int B){
  __shared__ int lh[512];
  int t = threadIdx.x, k = blockIdx.x;
  for (int b = t; b < B; b += 256) lh[b] = 0;
  __syncthreads();
  int base_i = k*CHUNK;
#pragma unroll
  for (int j = 0; j < CHUNK/256; ++j){
    int i = base_i + j*256 + t;
    if (i < e){
      int s = src[i], d = dst[i];
      int r = -1;
      if (s != d) r = atomicAdd(&lh[d>>BKT_SHIFT], 1);  // self-loops masked (PyG removes)
      rank[i] = r;
    }
  }
  __syncthreads();
  for (int b = t; b < B; b += 256) hist[k*B + b] = lh[b];
}

// pass 2: per-bucket exclusive scan over chunks (hist -> offs in-place)
__global__ __launch_bounds__(512) void csr_offs_kernel(
    int* __restrict__ hist, int* __restrict__ btotal, int NB, int B){
  __shared__ int s[512];
  int b = blockIdx.x, t = threadIdx.x;
  int v = (t < NB) ? hist[t*B + b] : 0;
  s[t] = v;
  __syncthreads();
  for (int off=1; off<512; off<<=1){
    int u = (t >= off) ? s[t-off] : 0;
    __syncthreads(); s[t] += u; __syncthreads();
  }
  int excl = s[t] - v;
  if (t < NB) hist[t*B + b] = excl;      // becomes offs[chunk][bucket]
  if (t == NB-1) btotal[b] = excl + v;
}

// pass 2b: bucket bases (exclusive scan of btotal, one block; B <= 512)
__global__ __launch_bounds__(512) void csr_base_kernel(
    const int* __restrict__ btotal, int* __restrict__ base, int B){
  __shared__ int s[512];
  int t = threadIdx.x;
  int v = (t < B) ? btotal[t] : 0;
  s[t] = v;
  __syncthreads();
  for (int off=1; off<512; off<<=1){
    int u = (t >= off) ? s[t-off] : 0;
    __syncthreads(); s[t] += u; __syncthreads();
  }
  if (t < B) base[t] = s[t] - v;
  if (t == B-1) base[B] = s[t];          // total valid edges
}

// pass 3: deterministic scatter to bucket-major packed array (no atomics)
__global__ __launch_bounds__(256) void csr_scatter_kernel(
    const int* __restrict__ src, const int* __restrict__ dst,
    const int* __restrict__ rank, const int* __restrict__ offs,
    const int* __restrict__ base, int* __restrict__ bpack, int e, int B){
  int t = threadIdx.x, k = blockIdx.x;
  int base_i = k*CHUNK;
#pragma unroll
  for (int j = 0; j < CHUNK/256; ++j){
    int i = base_i + j*256 + t;
    if (i < e){
      int r = rank[i];
      if (r >= 0){
        int d = dst[i], s = src[i];
        int b = d >> BKT_SHIFT;
        int pos = base[b] + offs[k*B + b] + r;
        bpack[pos] = (s << BKT_SHIFT) | (d & 127);   // s<2^16 -> fits 23 bits
      }
    }
  }
}

// pass 4: per-bucket counting sort -> csr (sequential writes) + indptr
__global__ __launch_bounds__(256) void csr_sort_kernel(
    const int* __restrict__ bpack, const int* __restrict__ base,
    int* __restrict__ csr, int* __restrict__ indptr, int n, int B){
  __shared__ int lh[128], cur[128], ss[128];
  int b = blockIdx.x, t = threadIdx.x;
  int beg = base[b], cnt = base[b+1] - beg;
  if (t < 128) lh[t] = 0;
  __syncthreads();
  for (int j = t; j < cnt; j += 256){
    int p = bpack[beg + j];
    atomicAdd(&lh[p & 127], 1);
  }
  __syncthreads();
  int v = (t < 128) ? lh[t] : 0;
  if (t < 128) ss[t] = v;
  __syncthreads();
  for (int off=1; off<128; off<<=1){
    int u = (t >= off && t < 128) ? ss[t-off] : 0;
    __syncthreads();
    if (t < 128) ss[t] += u;
    __syncthreads();
  }
  if (t < 128){
    int excl = ss[t] - v;
    cur[t] = excl;
    int node = (b << BKT_SHIFT) + t;
    if (node <= n) indptr[node] = beg + excl;   // node==n covered by last bucket
  }
  __syncthreads();
  for (int j = t; j < cnt; j += 256){
    int p = bpack[beg + j];
    int lpos = atomicAdd(&cur[p & 127], 1);
    csr[beg + lpos] = p >> BKT_SHIFT;
  }
}

// ---------------- MFMA GEMM: out[n,512] = X[n,K] * [Wl;Wr]^T + [bl;br] ----------------
// v_mfma_f32_16x16x32_f16. A operand = W (rows=channels), B operand = X
// (cols=nodes): C/D layout col=lane&15 (node), row=(lane>>4)*4+reg (channel)
// -> each frag epilogues as ONE contiguous h4 (8B) store per lane.
// X tile (64 nodes x K) staged LDS fp16; W frags direct from global (L2-resident).
template<int K, bool FUSE_COUNT>
__global__ __launch_bounds__(256, 2) void gemm_mfma(const float* __restrict__ X,
    const float* __restrict__ Wl, const float* __restrict__ bl,
    const float* __restrict__ Wr, const float* __restrict__ br,
    _Float16* __restrict__ outl, _Float16* __restrict__ outr, int n){
  const int KP = K + 8;
  __shared__ __align__(16) _Float16 Xs[64*(K+8)];
  int t = threadIdx.x;
  int n0 = blockIdx.x*64;
  int ybase = blockIdx.y;

  // stage X tile, fp32 -> fp16
  for (int idx = t; idx < 64*(K/4); idx += 256){
    int row = idx/(K/4), c = (idx%(K/4))*4;
    int node = n0 + row; if (node >= n) node = n-1;   // clamp; stores guarded
    float4 xv = *(const float4*)(X + (size_t)node*K + c);
    h4 hv = {(_Float16)xv.x, (_Float16)xv.y, (_Float16)xv.z, (_Float16)xv.w};
    *(h4*)(Xs + row*KP + c) = hv;
  }
  __syncthreads();

  int wave = t >> 6, lane = t & 63;
  int co = ybase*256 + wave*64;           // global channel base (0..511)
  const float* W   = (co < 256) ? Wl : Wr;
  const float* Bv  = (co < 256) ? bl : br;
  _Float16* outp   = (co < 256) ? outl : outr;
  int lco = co & 255;
  int lr = lane & 15, lg = lane >> 4;

  f32x4 acc[4][4];
#pragma unroll
  for (int c = 0; c < 4; ++c)
#pragma unroll
    for (int m = 0; m < 4; ++m) acc[c][m] = (f32x4){0.f, 0.f, 0.f, 0.f};

#pragma unroll
  for (int ks = 0; ks < K/32; ++ks){
    int k0 = ks*32 + lg*8;
    h8 a[4], b[4];
#pragma unroll
    for (int c = 0; c < 4; ++c){                 // A: W[ch][k0..k0+7], cvt f16
      const float* wp = W + (size_t)(lco + c*16 + lr)*K + k0;
      float4 w0 = *(const float4*)(wp);
      float4 w1 = *(const float4*)(wp + 4);
      a[c] = (h8){(_Float16)w0.x,(_Float16)w0.y,(_Float16)w0.z,(_Float16)w0.w,
                  (_Float16)w1.x,(_Float16)w1.y,(_Float16)w1.z,(_Float16)w1.w};
    }
#pragma unroll
    for (int m = 0; m < 4; ++m)                  // B: Xs[node][k0..k0+7]
      b[m] = *(const h8*)(Xs + (m*16 + lr)*KP + k0);
#pragma unroll
    for (int c = 0; c < 4; ++c)
#pragma unroll
      for (int m = 0; m < 4; ++m)
        acc[c][m] = __builtin_amdgcn_mfma_f32_16x16x32_f16(a[c], b[m], acc[c][m], 0, 0, 0);
  }

  // epilogue: frag (c,m): lane -> node n0+m*16+(lane&15), channels lco+c*16+lg*4+[0..3]
#pragma unroll
  for (int c = 0; c < 4; ++c){
    int ch = lco + c*16 + lg*4;
    float4 bb = *(const float4*)(Bv + ch);
#pragma unroll
    for (int m = 0; m < 4; ++m){
      int node = n0 + m*16 + lr;
      if (node < n){
        h4 o = {(_Float16)(acc[c][m][0] + bb.x), (_Float16)(acc[c][m][1] + bb.y),
                (_Float16)(acc[c][m][2] + bb.z), (_Float16)(acc[c][m][3] + bb.w)};
        *(h4*)(outp + (size_t)node*ODIM + ch) = o;
      }
    }
  }
}

// ---------------- fused edge softmax + aggregate, one wave per node ----------------
__global__ __launch_bounds__(256) void edge_kernel(
    const _Float16* __restrict__ xl, const _Float16* __restrict__ xr,
    const float* __restrict__ att, const float* __restrict__ bias,
    const int* __restrict__ indptr, const int* __restrict__ csr_src,
    float* __restrict__ out, int n, int act)
{
  int wid = blockIdx.x*4 + (threadIdx.x >> 6);
  if (wid >= n) return;
  int lane = threadIdx.x & 63;
  const float LOG2E = 1.44269504088896341f;

  float4 attf = *(const float4*)(att + 4*lane);
  h2 at0 = (h2){(_Float16)(attf.x*LOG2E), (_Float16)(attf.y*LOG2E)};
  h2 at1 = (h2){(_Float16)(attf.z*LOG2E), (_Float16)(attf.w*LOG2E)};
  const h2 c02 = {(_Float16)0.2f, (_Float16)0.2f};

  H4 xrh; xrh.v = *(const h4*)(xr + (size_t)wid*ODIM + 4*lane);
  H4 self; self.v = *(const h4*)(xl + (size_t)wid*ODIM + 4*lane);

  auto score = [&](const H4& c)->float{
    h2 t0 = c.p[0] + xrh.p[0];
    h2 t1 = c.p[1] + xrh.p[1];
    h2 q0 = __builtin_elementwise_max(t0, t0 * c02);
    h2 q1 = __builtin_elementwise_max(t1, t1 * c02);
    float d = FDOT2(q0, at0, FDOT2(q1, at1, 0.f));
    d += __shfl_xor(d, 1);   // reduce over the 8 lanes of this head
    d += __shfl_xor(d, 2);
    d += __shfl_xor(d, 4);
    return d;
  };

  // self-loop seeds the accumulator
  float w0 = exp2f(score(self));
  float denom = w0;
  float4 acc;
  acc.x = w0 * (float)self.v.x;
  acc.y = w0 * (float)self.v.y;
  acc.z = w0 * (float)self.v.z;
  acc.w = w0 * (float)self.v.w;

  int beg = __builtin_amdgcn_readfirstlane(indptr[wid]);
  int end = __builtin_amdgcn_readfirstlane(indptr[wid+1]);
  int cnt = end - beg;
  H4 r0, r1;
  r0.v = (h4){}; r1.v = (h4){};
  if (cnt > 0){
    int s0 = __builtin_amdgcn_readfirstlane(csr_src[beg]);
    r0.v = *(const h4*)(xl + (size_t)s0*ODIM + 4*lane);
  }
  if (cnt > 1){
    int s1 = __builtin_amdgcn_readfirstlane(csr_src[beg+1]);
    r1.v = *(const h4*)(xl + (size_t)s1*ODIM + 4*lane);
  }
  for (int k = 0; k < cnt; ++k){
    H4 cur = r0; r0 = r1;
    if (k+2 < cnt){
      int s2 = __builtin_amdgcn_readfirstlane(csr_src[beg+k+2]);
      r1.v = *(const h4*)(xl + (size_t)s2*ODIM + 4*lane);   // prefetch 2 ahead
    }
    float pe = exp2f(score(cur));
    denom += pe;
    acc.x = fmaf(pe, (float)cur.v.x, acc.x);   // v_fma_mix (single-use cvt)
    acc.y = fmaf(pe, (float)cur.v.y, acc.y);
    acc.z = fmaf(pe, (float)cur.v.z, acc.z);
    acc.w = fmaf(pe, (float)cur.v.w, acc.w);
  }
  float inv = 1.f/denom;
  float vx = acc.x*inv, vy = acc.y*inv, vz = acc.z*inv, vw = acc.w*inv;
  // mean over heads: sum lanes {l, l^8, l^16, l^32}
  vx += __shfl_xor(vx, 8);  vx += __shfl_xor(vx, 16);  vx += __shfl_xor(vx, 32);
  vy += __shfl_xor(vy, 8);  vy += __shfl_xor(vy, 16);  vy += __shfl_xor(vy, 32);
  vz += __shfl_xor(vz, 8);  vz += __shfl_xor(vz, 16);  vz += __shfl_xor(vz, 32);
  vw += __shfl_xor(vw, 8);  vw += __shfl_xor(vw, 16);  vw += __shfl_xor(vw, 32);
  if (lane < 8){
    float4 bv = *(const float4*)(bias + 4*lane);
    float ox = vx*0.125f + bv.x;
    float oy = vy*0.125f + bv.y;
    float oz = vz*0.125f + bv.z;
    float ow = vw*0.125f + bv.w;
    if (act){
      ox = lrelu(ox, 0.01f); oy = lrelu(oy, 0.01f);
      oz = lrelu(oz, 0.01f); ow = lrelu(ow, 0.01f);
    }
    *(float4*)(out + (size_t)wid*CDIM + 4*lane) = make_float4(ox, oy, oz, ow);
  }
}

extern "C" void kernel_launch(void* const* d_in, const int* in_sizes, int n_in,
                              void* d_out, int out_size, void* d_ws, size_t ws_size,
                              hipStream_t stream){
  (void)n_in; (void)out_size; (void)ws_size;
  const float* x    = (const float*)d_in[0];
  const int*   ei   = (const int*)d_in[1];
  const float* W1l  = (const float*)d_in[2];
  const float* b1l  = (const float*)d_in[3];
  const float* W1r  = (const float*)d_in[4];
  const float* b1r  = (const float*)d_in[5];
  const float* att1 = (const float*)d_in[6];
  const float* bias1= (const float*)d_in[7];
  const float* W2l  = (const float*)d_in[8];
  const float* b2l  = (const float*)d_in[9];
  const float* W2r  = (const float*)d_in[10];
  const float* b2r  = (const float*)d_in[11];
  const float* att2 = (const float*)d_in[12];
  const float* bias2= (const float*)d_in[13];
  int n = in_sizes[0] / 64;   // 50000
  int e = in_sizes[1] / 2;    // 800000
  const int* src = ei;
  const int* dst = ei + e;

  char* ws = (char*)d_ws;
  size_t off = 0;
  auto alloc = [&](size_t bytes)->char*{
    char* p = ws + off; off += (bytes + 255) & ~(size_t)255; return p;
  };
  _Float16* xl  = (_Float16*)alloc((size_t)n*ODIM*2);  // 25.6 MB fp16
  _Float16* xr  = (_Float16*)alloc((size_t)n*ODIM*2);  // 25.6 MB fp16
  float* h      = (float*)alloc((size_t)n*CDIM*4);     // 6.4 MB layer-1 output
  int*   indptr = (int*)alloc((size_t)(n+1)*4);
  int*   rank   = (int*)alloc((size_t)e*4);
  int*   csr    = (int*)alloc((size_t)e*4);
  int*   bpack  = (int*)alloc((size_t)e*4);

  int NB = (e + CHUNK-1) / CHUNK;   // 391 edge chunks
  int B  = (n + 127) >> 7;          // 391 buckets of 128 nodes
  int*   hist   = (int*)alloc((size_t)NB*B*4);         // 611 KB (becomes offs)
  int*   btotal = (int*)alloc((size_t)B*4);
  int*   base   = (int*)alloc((size_t)(B+1)*4);

  int nt64 = (n + 63) / 64;         // 782

  // ---- CSR build: zero global atomics (R2: atomics were the 72us floor) ----
  csr_hist_kernel<<<NB, 256, 0, stream>>>(src, dst, rank, hist, e, B);
  csr_offs_kernel<<<B, 512, 0, stream>>>(hist, btotal, NB, B);
  csr_base_kernel<<<1, 512, 0, stream>>>(btotal, base, B);
  csr_scatter_kernel<<<NB, 256, 0, stream>>>(src, dst, rank, hist, base, bpack, e, B);
  csr_sort_kernel<<<B, 256, 0, stream>>>(bpack, base, csr, indptr, n, B);

  // ---- layer 1 ----
  gemm_mfma<64,false><<<dim3(nt64,2), 256, 0, stream>>>(
      x, W1l, b1l, W1r, b1r, xl, xr, n);
  edge_kernel<<<(n+3)/4, 256, 0, stream>>>(xl, xr, att1, bias1, indptr, csr, h, n, 1);
  // ---- layer 2 ----
  gemm_mfma<32,false><<<dim3(nt64,2), 256, 0, stream>>>(
      h, W2l, b2l, W2r, b2r, xl, xr, n);
  edge_kernel<<<(n+3)/4, 256, 0, stream>>>(xl, xr, att2, bias2, indptr, csr, (float*)d_out, n, 0);
}

// Round 4
// 310.549 us; speedup vs baseline: 1.0854x; 1.0303x over previous
//
#include <hip/hip_runtime.h>
#include <math.h>

// GATv2 2-layer: N=50000, E=800000, HEADS=8, C=32, ODIM=256, IN_C=64
#define HEADS 8
#define CDIM 32
#define ODIM 256
#define BKT_SHIFT 7              // 128 nodes per bucket
#define CHUNK 2048               // edges per histogram chunk

typedef _Float16 h2 __attribute__((ext_vector_type(2)));
typedef _Float16 h4 __attribute__((ext_vector_type(4)));
typedef _Float16 h8 __attribute__((ext_vector_type(8)));
typedef float f32x4 __attribute__((ext_vector_type(4)));
union H4 { h4 v; h2 p[2]; };

#if __has_builtin(__builtin_amdgcn_fdot2)
#define FDOT2(a,b,c) __builtin_amdgcn_fdot2((a),(b),(c),false)
#else
static __device__ __forceinline__ float fdot2_sw(h2 a, h2 b, float c){
  return fmaf((float)a.x, (float)b.x, fmaf((float)a.y, (float)b.y, c));
}
#define FDOT2(a,b,c) fdot2_sw((a),(b),(c))
#endif

__device__ __forceinline__ float lrelu(float v, float s){ return fmaxf(v, s*v); }

// ================= atomic-free CSR build (bucket counting sort) =================
// R2: 800K device-scope atomicAdd = 72us floor. R3: LDS-only 5-pass sort works;
// R4: hist pass fused into gemm1's grid (y==2 slice) to overlap with the GEMM.

// pass 2: per-bucket exclusive scan over chunks (hist -> offs in-place)
__global__ __launch_bounds__(512) void csr_offs_kernel(
    int* __restrict__ hist, int* __restrict__ btotal, int NB, int B){
  __shared__ int s[512];
  int b = blockIdx.x, t = threadIdx.x;
  int v = (t < NB) ? hist[t*B + b] : 0;
  s[t] = v;
  __syncthreads();
  for (int off=1; off<512; off<<=1){
    int u = (t >= off) ? s[t-off] : 0;
    __syncthreads(); s[t] += u; __syncthreads();
  }
  int excl = s[t] - v;
  if (t < NB) hist[t*B + b] = excl;      // becomes offs[chunk][bucket]
  if (t == NB-1) btotal[b] = excl + v;
}

// pass 2b: bucket bases (exclusive scan of btotal, one block; B <= 512)
__global__ __launch_bounds__(512) void csr_base_kernel(
    const int* __restrict__ btotal, int* __restrict__ base, int B){
  __shared__ int s[512];
  int t = threadIdx.x;
  int v = (t < B) ? btotal[t] : 0;
  s[t] = v;
  __syncthreads();
  for (int off=1; off<512; off<<=1){
    int u = (t >= off) ? s[t-off] : 0;
    __syncthreads(); s[t] += u; __syncthreads();
  }
  if (t < B) base[t] = s[t] - v;
  if (t == B-1) base[B] = s[t];          // total valid edges
}

// pass 3: deterministic scatter to bucket-major packed array (no atomics)
__global__ __launch_bounds__(256) void csr_scatter_kernel(
    const int* __restrict__ src, const int* __restrict__ dst,
    const int* __restrict__ rank, const int* __restrict__ offs,
    const int* __restrict__ base, int* __restrict__ bpack, int e, int B){
  int t = threadIdx.x, k = blockIdx.x;
  int base_i = k*CHUNK;
#pragma unroll
  for (int j = 0; j < CHUNK/256; ++j){
    int i = base_i + j*256 + t;
    if (i < e){
      int r = rank[i];
      if (r >= 0){
        int d = dst[i], s = src[i];
        int b = d >> BKT_SHIFT;
        int pos = base[b] + offs[k*B + b] + r;
        bpack[pos] = (s << BKT_SHIFT) | (d & 127);   // s<2^16 -> fits 23 bits
      }
    }
  }
}

// pass 4: per-bucket counting sort -> csr (sequential writes) + indptr
__global__ __launch_bounds__(256) void csr_sort_kernel(
    const int* __restrict__ bpack, const int* __restrict__ base,
    int* __restrict__ csr, int* __restrict__ indptr, int n, int B){
  __shared__ int lh[128], cur[128], ss[128];
  int b = blockIdx.x, t = threadIdx.x;
  int beg = base[b], cnt = base[b+1] - beg;
  if (t < 128) lh[t] = 0;
  __syncthreads();
  for (int j = t; j < cnt; j += 256){
    int p = bpack[beg + j];
    atomicAdd(&lh[p & 127], 1);
  }
  __syncthreads();
  int v = (t < 128) ? lh[t] : 0;
  if (t < 128) ss[t] = v;
  __syncthreads();
  for (int off=1; off<128; off<<=1){
    int u = (t >= off && t < 128) ? ss[t-off] : 0;
    __syncthreads();
    if (t < 128) ss[t] += u;
    __syncthreads();
  }
  if (t < 128){
    int excl = ss[t] - v;
    cur[t] = excl;
    int node = (b << BKT_SHIFT) + t;
    if (node <= n) indptr[node] = beg + excl;   // node==n covered by last bucket
  }
  __syncthreads();
  for (int j = t; j < cnt; j += 256){
    int p = bpack[beg + j];
    int lpos = atomicAdd(&cur[p & 127], 1);
    csr[beg + lpos] = p >> BKT_SHIFT;
  }
}

// ---------------- MFMA GEMM: out[n,512] = X[n,K] * [Wl;Wr]^T + [bl;br] ----------------
// v_mfma_f32_16x16x32_f16. A operand = W (rows=channels), B operand = X
// (cols=nodes): C/D layout col=lane&15 (node), row=(lane>>4)*4+reg (channel)
// -> each frag epilogues as ONE contiguous h4 (8B) store per lane.
// X tile (64 nodes x K) staged LDS fp16; W frags direct from global (L2-resident).
// FUSE_HIST: y==2 slice (x < NB) runs the CSR bucket histogram (LDS atomics
// only) concurrently with the GEMM blocks -> saves one serialized dispatch.
template<int K, bool FUSE_HIST>
__global__ __launch_bounds__(256, 2) void gemm_mfma(const float* __restrict__ X,
    const float* __restrict__ Wl, const float* __restrict__ bl,
    const float* __restrict__ Wr, const float* __restrict__ br,
    _Float16* __restrict__ outl, _Float16* __restrict__ outr, int n,
    const int* __restrict__ src, const int* __restrict__ dst,
    int* __restrict__ rank, int* __restrict__ hist, int e, int B){
  if (FUSE_HIST && blockIdx.y == 2){
    int k = blockIdx.x;
    int NB = (e + CHUNK-1)/CHUNK;
    if (k >= NB) return;
    __shared__ int lh[512];
    int t = threadIdx.x;
    for (int b = t; b < B; b += 256) lh[b] = 0;
    __syncthreads();
    int base_i = k*CHUNK;
#pragma unroll
    for (int j = 0; j < CHUNK/256; ++j){
      int i = base_i + j*256 + t;
      if (i < e){
        int s = src[i], d = dst[i];
        int r = -1;
        if (s != d) r = atomicAdd(&lh[d>>BKT_SHIFT], 1);  // self-loops masked
        rank[i] = r;
      }
    }
    __syncthreads();
    for (int b = t; b < B; b += 256) hist[k*B + b] = lh[b];
    return;
  }
  const int KP = K + 8;
  __shared__ __align__(16) _Float16 Xs[64*(K+8)];
  int t = threadIdx.x;
  int n0 = blockIdx.x*64;
  int ybase = blockIdx.y;

  // stage X tile, fp32 -> fp16
  for (int idx = t; idx < 64*(K/4); idx += 256){
    int row = idx/(K/4), c = (idx%(K/4))*4;
    int node = n0 + row; if (node >= n) node = n-1;   // clamp; stores guarded
    float4 xv = *(const float4*)(X + (size_t)node*K + c);
    h4 hv = {(_Float16)xv.x, (_Float16)xv.y, (_Float16)xv.z, (_Float16)xv.w};
    *(h4*)(Xs + row*KP + c) = hv;
  }
  __syncthreads();

  int wave = t >> 6, lane = t & 63;
  int co = ybase*256 + wave*64;           // global channel base (0..511)
  const float* W   = (co < 256) ? Wl : Wr;
  const float* Bv  = (co < 256) ? bl : br;
  _Float16* outp   = (co < 256) ? outl : outr;
  int lco = co & 255;
  int lr = lane & 15, lg = lane >> 4;

  f32x4 acc[4][4];
#pragma unroll
  for (int c = 0; c < 4; ++c)
#pragma unroll
    for (int m = 0; m < 4; ++m) acc[c][m] = (f32x4){0.f, 0.f, 0.f, 0.f};

#pragma unroll
  for (int ks = 0; ks < K/32; ++ks){
    int k0 = ks*32 + lg*8;
    h8 a[4], b[4];
#pragma unroll
    for (int c = 0; c < 4; ++c){                 // A: W[ch][k0..k0+7], cvt f16
      const float* wp = W + (size_t)(lco + c*16 + lr)*K + k0;
      float4 w0 = *(const float4*)(wp);
      float4 w1 = *(const float4*)(wp + 4);
      a[c] = (h8){(_Float16)w0.x,(_Float16)w0.y,(_Float16)w0.z,(_Float16)w0.w,
                  (_Float16)w1.x,(_Float16)w1.y,(_Float16)w1.z,(_Float16)w1.w};
    }
#pragma unroll
    for (int m = 0; m < 4; ++m)                  // B: Xs[node][k0..k0+7]
      b[m] = *(const h8*)(Xs + (m*16 + lr)*KP + k0);
#pragma unroll
    for (int c = 0; c < 4; ++c)
#pragma unroll
      for (int m = 0; m < 4; ++m)
        acc[c][m] = __builtin_amdgcn_mfma_f32_16x16x32_f16(a[c], b[m], acc[c][m], 0, 0, 0);
  }

  // epilogue: frag (c,m): lane -> node n0+m*16+(lane&15), channels lco+c*16+lg*4+[0..3]
#pragma unroll
  for (int c = 0; c < 4; ++c){
    int ch = lco + c*16 + lg*4;
    float4 bb = *(const float4*)(Bv + ch);
#pragma unroll
    for (int m = 0; m < 4; ++m){
      int node = n0 + m*16 + lr;
      if (node < n){
        h4 o = {(_Float16)(acc[c][m][0] + bb.x), (_Float16)(acc[c][m][1] + bb.y),
                (_Float16)(acc[c][m][2] + bb.z), (_Float16)(acc[c][m][3] + bb.w)};
        *(h4*)(outp + (size_t)node*ODIM + ch) = o;
      }
    }
  }
}

// ---------------- fused edge softmax + aggregate, one wave per node ----------------
// R4 rewrite: (a) adjacency indices loaded ONCE per 64-edge chunk as a single
// contiguous 256B wave read + __shfl broadcast (removes the per-edge scalar
// csr load -> gather serial double-latency of R3); (b) 2 edges/iter with a
// 4-deep prefetch ring (~440 cyc cover vs ~500 cyc L2-miss latency, 2 indep
// score chains of ILP, half the loop/mov overhead).
__global__ __launch_bounds__(256) void edge_kernel(
    const _Float16* __restrict__ xl, const _Float16* __restrict__ xr,
    const float* __restrict__ att, const float* __restrict__ bias,
    const int* __restrict__ indptr, const int* __restrict__ csr_src,
    float* __restrict__ out, int n, int act)
{
  int wid = blockIdx.x*4 + (threadIdx.x >> 6);
  if (wid >= n) return;
  int lane = threadIdx.x & 63;
  const float LOG2E = 1.44269504088896341f;

  float4 attf = *(const float4*)(att + 4*lane);
  h2 at0 = (h2){(_Float16)(attf.x*LOG2E), (_Float16)(attf.y*LOG2E)};
  h2 at1 = (h2){(_Float16)(attf.z*LOG2E), (_Float16)(attf.w*LOG2E)};
  const h2 c02 = {(_Float16)0.2f, (_Float16)0.2f};

  H4 xrh; xrh.v = *(const h4*)(xr + (size_t)wid*ODIM + 4*lane);
  H4 self; self.v = *(const h4*)(xl + (size_t)wid*ODIM + 4*lane);

  auto score = [&](const H4& c)->float{
    h2 t0 = c.p[0] + xrh.p[0];
    h2 t1 = c.p[1] + xrh.p[1];
    h2 q0 = __builtin_elementwise_max(t0, t0 * c02);
    h2 q1 = __builtin_elementwise_max(t1, t1 * c02);
    float d = FDOT2(q0, at0, FDOT2(q1, at1, 0.f));
    d += __shfl_xor(d, 1);   // reduce over the 8 lanes of this head
    d += __shfl_xor(d, 2);
    d += __shfl_xor(d, 4);
    return d;
  };

  // self-loop seeds the accumulator
  float w0 = exp2f(score(self));
  float denom = w0;
  float4 acc;
  acc.x = w0 * (float)self.v.x;
  acc.y = w0 * (float)self.v.y;
  acc.z = w0 * (float)self.v.z;
  acc.w = w0 * (float)self.v.w;

  int beg = __builtin_amdgcn_readfirstlane(indptr[wid]);
  int end = __builtin_amdgcn_readfirstlane(indptr[wid+1]);
  int cnt = end - beg;

#define GATHER(j) (*(const h4*)(xl + (size_t)((unsigned)__shfl(sidx,(j)))*ODIM + 4*lane))
  for (int cb = 0; cb < cnt; cb += 64){          // 64-edge chunks (deg>64 safe)
    int ccnt = min(cnt - cb, 64);
    int sidx = (lane < ccnt) ? csr_src[beg + cb + lane] : 0;  // 256B wave read
    H4 r0, r1, r2, r3;
    r0.v = (h4){}; r1.v = (h4){}; r2.v = (h4){}; r3.v = (h4){};
    if (ccnt > 0) r0.v = GATHER(0);
    if (ccnt > 1) r1.v = GATHER(1);
    if (ccnt > 2) r2.v = GATHER(2);
    if (ccnt > 3) r3.v = GATHER(3);
#pragma unroll 2
    for (int k = 0; k < ccnt; k += 2){
      H4 e0 = r0, e1 = r1;
      r0 = r2; r1 = r3;
      if (k+4 < ccnt) r2.v = GATHER(k+4);        // prefetch 4 edges ahead
      if (k+5 < ccnt) r3.v = GATHER(k+5);
      float s0 = score(e0);
      float s1 = score(e1);
      float pe0 = exp2f(s0);
      float pe1 = (k+1 < ccnt) ? exp2f(s1) : 0.f;  // tail guard (e1 may be stale)
      denom += pe0 + pe1;
      acc.x = fmaf(pe0, (float)e0.v.x, fmaf(pe1, (float)e1.v.x, acc.x));
      acc.y = fmaf(pe0, (float)e0.v.y, fmaf(pe1, (float)e1.v.y, acc.y));
      acc.z = fmaf(pe0, (float)e0.v.z, fmaf(pe1, (float)e1.v.z, acc.z));
      acc.w = fmaf(pe0, (float)e0.v.w, fmaf(pe1, (float)e1.v.w, acc.w));
    }
  }
#undef GATHER

  float inv = 1.f/denom;
  float vx = acc.x*inv, vy = acc.y*inv, vz = acc.z*inv, vw = acc.w*inv;
  // mean over heads: sum lanes {l, l^8, l^16, l^32}
  vx += __shfl_xor(vx, 8);  vx += __shfl_xor(vx, 16);  vx += __shfl_xor(vx, 32);
  vy += __shfl_xor(vy, 8);  vy += __shfl_xor(vy, 16);  vy += __shfl_xor(vy, 32);
  vz += __shfl_xor(vz, 8);  vz += __shfl_xor(vz, 16);  vz += __shfl_xor(vz, 32);
  vw += __shfl_xor(vw, 8);  vw += __shfl_xor(vw, 16);  vw += __shfl_xor(vw, 32);
  if (lane < 8){
    float4 bv = *(const float4*)(bias + 4*lane);
    float ox = vx*0.125f + bv.x;
    float oy = vy*0.125f + bv.y;
    float oz = vz*0.125f + bv.z;
    float ow = vw*0.125f + bv.w;
    if (act){
      ox = lrelu(ox, 0.01f); oy = lrelu(oy, 0.01f);
      oz = lrelu(oz, 0.01f); ow = lrelu(ow, 0.01f);
    }
    *(float4*)(out + (size_t)wid*CDIM + 4*lane) = make_float4(ox, oy, oz, ow);
  }
}

extern "C" void kernel_launch(void* const* d_in, const int* in_sizes, int n_in,
                              void* d_out, int out_size, void* d_ws, size_t ws_size,
                              hipStream_t stream){
  (void)n_in; (void)out_size; (void)ws_size;
  const float* x    = (const float*)d_in[0];
  const int*   ei   = (const int*)d_in[1];
  const float* W1l  = (const float*)d_in[2];
  const float* b1l  = (const float*)d_in[3];
  const float* W1r  = (const float*)d_in[4];
  const float* b1r  = (const float*)d_in[5];
  const float* att1 = (const float*)d_in[6];
  const float* bias1= (const float*)d_in[7];
  const float* W2l  = (const float*)d_in[8];
  const float* b2l  = (const float*)d_in[9];
  const float* W2r  = (const float*)d_in[10];
  const float* b2r  = (const float*)d_in[11];
  const float* att2 = (const float*)d_in[12];
  const float* bias2= (const float*)d_in[13];
  int n = in_sizes[0] / 64;   // 50000
  int e = in_sizes[1] / 2;    // 800000
  const int* src = ei;
  const int* dst = ei + e;

  char* ws = (char*)d_ws;
  size_t off = 0;
  auto alloc = [&](size_t bytes)->char*{
    char* p = ws + off; off += (bytes + 255) & ~(size_t)255; return p;
  };
  _Float16* xl  = (_Float16*)alloc((size_t)n*ODIM*2);  // 25.6 MB fp16
  _Float16* xr  = (_Float16*)alloc((size_t)n*ODIM*2);  // 25.6 MB fp16
  float* h      = (float*)alloc((size_t)n*CDIM*4);     // 6.4 MB layer-1 output
  int*   indptr = (int*)alloc((size_t)(n+1)*4);
  int*   rank   = (int*)alloc((size_t)e*4);
  int*   csr    = (int*)alloc((size_t)e*4);
  int*   bpack  = (int*)alloc((size_t)e*4);

  int NB = (e + CHUNK-1) / CHUNK;   // 391 edge chunks
  int B  = (n + 127) >> 7;          // 391 buckets of 128 nodes
  int*   hist   = (int*)alloc((size_t)NB*B*4);         // 611 KB (becomes offs)
  int*   btotal = (int*)alloc((size_t)B*4);
  int*   base   = (int*)alloc((size_t)(B+1)*4);

  int nt64 = (n + 63) / 64;         // 782

  // ---- layer-1 GEMM with fused CSR histogram (y==2 slice) ----
  gemm_mfma<64,true><<<dim3(nt64,3), 256, 0, stream>>>(
      x, W1l, b1l, W1r, b1r, xl, xr, n, src, dst, rank, hist, e, B);
  // ---- rest of atomic-free CSR build ----
  csr_offs_kernel<<<B, 512, 0, stream>>>(hist, btotal, NB, B);
  csr_base_kernel<<<1, 512, 0, stream>>>(btotal, base, B);
  csr_scatter_kernel<<<NB, 256, 0, stream>>>(src, dst, rank, hist, base, bpack, e, B);
  csr_sort_kernel<<<B, 256, 0, stream>>>(bpack, base, csr, indptr, n, B);

  edge_kernel<<<(n+3)/4, 256, 0, stream>>>(xl, xr, att1, bias1, indptr, csr, h, n, 1);
  // ---- layer 2 ----
  gemm_mfma<32,false><<<dim3(nt64,2), 256, 0, stream>>>(
      h, W2l, b2l, W2r, b2r, xl, xr, n, nullptr, nullptr, nullptr, nullptr, 0, 0);
  edge_kernel<<<(n+3)/4, 256, 0, stream>>>(xl, xr, att2, bias2, indptr, csr, (float*)d_out, n, 0);
}